// Round 1
// baseline (592.636 us; speedup 1.0000x reference)
//
#include <hip/hip_runtime.h>

// 2-layer LSTM, B=1024 T=512 D=1 H=64, batch-parallel across blocks.
// Block = 16 batches, 4 waves. Weights as f16 MFMA B-frags in registers
// (wave w owns N-tiles {w,w+4,w+8,w+12} so each lane's D-frag has complete
// i,f,g,o for its hidden units -> pointwise fully in registers).
// h state crosses LDS as f16 (A-frag layout, rows padded to 72 halves),
// double-buffered by t parity -> 2 barriers/step.

typedef _Float16 f16x8 __attribute__((ext_vector_type(8)));
typedef float f32x4 __attribute__((ext_vector_type(4)));

#define TSTEPS 512
#define MB 16           // batches per block
#define HPAD 72         // padded row (halves); 144B = 9*16B, bank-friendly

__device__ __forceinline__ float sig_from_scaled(float a) {
    // a = -log2e * pre ; sigmoid(pre) = 1/(1+2^a)
    return __builtin_amdgcn_rcpf(1.f + __builtin_amdgcn_exp2f(a));
}
__device__ __forceinline__ float tanh_from_scaled(float a) {
    // a = 2*log2e * pre ; tanh(pre) = 1 - 2/(1+2^a)
    return 1.f - 2.f * __builtin_amdgcn_rcpf(1.f + __builtin_amdgcn_exp2f(a));
}

__global__ __launch_bounds__(256) void lstm2_kernel(
    const float* __restrict__ x,
    const float* __restrict__ W_ih0, const float* __restrict__ W_hh0,
    const float* __restrict__ b_ih0, const float* __restrict__ b_hh0,
    const float* __restrict__ W_ih1, const float* __restrict__ W_hh1,
    const float* __restrict__ b_ih1, const float* __restrict__ b_hh1,
    const float* __restrict__ W_fc,  const float* __restrict__ b_fc,
    float* __restrict__ out)
{
    __shared__ _Float16 h0s[2][MB * HPAD];
    __shared__ _Float16 h1s[2][MB * HPAD];
    __shared__ float    xlds[64 * 20];       // [step-in-chunk][m], pad 20

    const int tid  = (int)threadIdx.x;
    const int lane = tid & 63;
    const int w    = tid >> 6;          // wave 0..3
    const int c    = lane & 15;         // n within tile / m for A-frags
    const int quad = lane >> 4;         // 0..3
    const int j    = (w << 4) | c;      // hidden index 0..63 owned by this lane
    const int b0   = (int)blockIdx.x * MB;

    const float L2E = 1.44269504088896340736f;

    // ---- per-lane constants & register-resident weight fragments ----
    float bias0c[4], wih0c[4], bias1c[4];
    f16x8 bf0[4][2];   // layer0: gate g, K-chunk kb
    f16x8 bf1[4][4];   // layer1: gate g, K-chunk kb (K=128: [W_ih1 | W_hh1])

#pragma unroll
    for (int g = 0; g < 4; ++g) {
        const int n = j + 64 * g;
        const float sg = (g == 2) ? (2.0f * L2E) : (-L2E);
        bias0c[g] = sg * (b_ih0[n] + b_hh0[n]);
        wih0c[g]  = sg * W_ih0[n];                    // D == 1
        bias1c[g] = sg * (b_ih1[n] + b_hh1[n]);
#pragma unroll
        for (int kb = 0; kb < 2; ++kb) {
            const float* p = W_hh0 + n * 64 + kb * 32 + quad * 8;
#pragma unroll
            for (int q = 0; q < 8; ++q) bf0[g][kb][q] = (_Float16)(p[q] * sg);
        }
#pragma unroll
        for (int kb = 0; kb < 4; ++kb) {
            const int kk = kb * 32 + quad * 8;
            const float* p = (kk < 64) ? (W_ih1 + n * 64 + kk)
                                       : (W_hh1 + n * 64 + (kk - 64));
#pragma unroll
            for (int q = 0; q < 8; ++q) bf1[g][kb][q] = (_Float16)(p[q] * sg);
        }
    }

    // zero-init h buffers (h(-1) = 0)
    for (int i = tid; i < MB * HPAD; i += 256) {
        h0s[0][i] = (_Float16)0.f; h0s[1][i] = (_Float16)0.f;
        h1s[0][i] = (_Float16)0.f; h1s[1][i] = (_Float16)0.f;
    }

    float c0[4] = {0.f, 0.f, 0.f, 0.f};
    float c1[4] = {0.f, 0.f, 0.f, 0.f};

    for (int t = 0; t < TSTEPS; ++t) {
        if ((t & 63) == 0) {
            __syncthreads();                 // prior xlds reads / h-init done
            const int m = tid & 15, ii = tid >> 4;
#pragma unroll
            for (int p4 = 0; p4 < 4; ++p4) {
                const int i = ii + 16 * p4;
                xlds[i * 20 + m] = x[(b0 + m) * TSTEPS + t + i];
            }
            __syncthreads();
        }
        const int pr = t & 1, pw = pr ^ 1;

        // ================= layer 0 =================
        // C-init = scaled(bias + x*W_ih0); A = h0(t-1) f16; B = scaled W_hh0
        const f32x4 xv = *(const f32x4*)&xlds[(t & 63) * 20 + quad * 4];
        f32x4 acc[4];
#pragma unroll
        for (int g = 0; g < 4; ++g)
#pragma unroll
            for (int r = 0; r < 4; ++r) acc[g][r] = bias0c[g] + xv[r] * wih0c[g];

        const f16x8 a0 = *(const f16x8*)&h0s[pr][c * HPAD + 0 * 32 + quad * 8];
        const f16x8 a1 = *(const f16x8*)&h0s[pr][c * HPAD + 1 * 32 + quad * 8];
#pragma unroll
        for (int g = 0; g < 4; ++g) {
            acc[g] = __builtin_amdgcn_mfma_f32_16x16x32_f16(a0, bf0[g][0], acc[g], 0, 0, 0);
            acc[g] = __builtin_amdgcn_mfma_f32_16x16x32_f16(a1, bf0[g][1], acc[g], 0, 0, 0);
        }
        // pointwise (units: m = quad*4 + r, hidden j) — all in registers
#pragma unroll
        for (int r = 0; r < 4; ++r) {
            const float i_ = sig_from_scaled(acc[0][r]);
            const float f_ = sig_from_scaled(acc[1][r]);
            const float g_ = tanh_from_scaled(acc[2][r]);
            const float o_ = sig_from_scaled(acc[3][r]);
            const float cc = f_ * c0[r] + i_ * g_;
            c0[r] = cc;
            const float th = tanh_from_scaled(cc * (2.f * L2E));
            h0s[pw][(quad * 4 + r) * HPAD + j] = (_Float16)(o_ * th);
        }
        __syncthreads();   // h0(t) visible for layer 1

        // ================= layer 1 =================
#pragma unroll
        for (int g = 0; g < 4; ++g)
#pragma unroll
            for (int r = 0; r < 4; ++r) acc[g][r] = bias1c[g];

        const f16x8 a10 = *(const f16x8*)&h0s[pw][c * HPAD + 0 * 32 + quad * 8];
        const f16x8 a11 = *(const f16x8*)&h0s[pw][c * HPAD + 1 * 32 + quad * 8];
        const f16x8 a12 = *(const f16x8*)&h1s[pr][c * HPAD + 0 * 32 + quad * 8];
        const f16x8 a13 = *(const f16x8*)&h1s[pr][c * HPAD + 1 * 32 + quad * 8];
#pragma unroll
        for (int g = 0; g < 4; ++g) {
            acc[g] = __builtin_amdgcn_mfma_f32_16x16x32_f16(a10, bf1[g][0], acc[g], 0, 0, 0);
            acc[g] = __builtin_amdgcn_mfma_f32_16x16x32_f16(a11, bf1[g][1], acc[g], 0, 0, 0);
            acc[g] = __builtin_amdgcn_mfma_f32_16x16x32_f16(a12, bf1[g][2], acc[g], 0, 0, 0);
            acc[g] = __builtin_amdgcn_mfma_f32_16x16x32_f16(a13, bf1[g][3], acc[g], 0, 0, 0);
        }
#pragma unroll
        for (int r = 0; r < 4; ++r) {
            const float i_ = sig_from_scaled(acc[0][r]);
            const float f_ = sig_from_scaled(acc[1][r]);
            const float g_ = tanh_from_scaled(acc[2][r]);
            const float o_ = sig_from_scaled(acc[3][r]);
            const float cc = f_ * c1[r] + i_ * g_;
            c1[r] = cc;
            const float th = tanh_from_scaled(cc * (2.f * L2E));
            h1s[pw][(quad * 4 + r) * HPAD + j] = (_Float16)(o_ * th);
        }
        __syncthreads();   // h1(t) visible for next step
    }

    // ---- epilogue: out[b] = h0f . W_fc + b_fc ; out[1024+b] = h1f . W_fc + b_fc
    // final write buffer index: (TSTEPS-1+1)&1 = 0
    if (tid < 32) {
        const int which = tid >> 4, m = tid & 15;
        const _Float16* hb = which ? &h1s[0][m * HPAD] : &h0s[0][m * HPAD];
        float s = b_fc[0];
        for (int jj = 0; jj < 64; ++jj) s += (float)hb[jj] * W_fc[jj];
        out[which * 1024 + b0 + m] = s;
    }
}

extern "C" void kernel_launch(void* const* d_in, const int* in_sizes, int n_in,
                              void* d_out, int out_size, void* d_ws, size_t ws_size,
                              hipStream_t stream) {
    (void)in_sizes; (void)n_in; (void)d_ws; (void)ws_size; (void)out_size;
    lstm2_kernel<<<64, 256, 0, stream>>>(
        (const float*)d_in[0],
        (const float*)d_in[1], (const float*)d_in[2],
        (const float*)d_in[3], (const float*)d_in[4],
        (const float*)d_in[5], (const float*)d_in[6],
        (const float*)d_in[7], (const float*)d_in[8],
        (const float*)d_in[9], (const float*)d_in[10],
        (float*)d_out);
}

// Round 2
// 451.790 us; speedup vs baseline: 1.3118x; 1.3118x over previous
//
#include <hip/hip_runtime.h>

// 2-layer LSTM, B=1024 T=512 D=1 H=64. 64 blocks x 512 threads.
// Software pipeline across wave groups: waves 0-3 (group A) compute
// layer0 step t while waves 4-7 (group B) compute layer1 step t-1.
// One __syncthreads per iteration (parity double-buffers for h0,h1).
// Weights live in registers as f16 MFMA B-frags, per-group only.

typedef _Float16 f16x8 __attribute__((ext_vector_type(8)));
typedef float f32x4 __attribute__((ext_vector_type(4)));

#define TSTEPS 512
#define MB 16           // batches per block (MFMA M)
#define HPAD 72         // padded row in halves; 144B

__device__ __forceinline__ float sig_from_scaled(float a) {
    // a = -log2e * pre ; sigmoid(pre) = 1/(1+2^a)
    return __builtin_amdgcn_rcpf(1.f + __builtin_amdgcn_exp2f(a));
}
__device__ __forceinline__ float tanh_from_scaled(float a) {
    // a = 2*log2e * pre ; tanh(pre) = 1 - 2/(1+2^a)
    return 1.f - 2.f * __builtin_amdgcn_rcpf(1.f + __builtin_amdgcn_exp2f(a));
}

__global__ __launch_bounds__(512) void lstm2_kernel(
    const float* __restrict__ x,
    const float* __restrict__ W_ih0, const float* __restrict__ W_hh0,
    const float* __restrict__ b_ih0, const float* __restrict__ b_hh0,
    const float* __restrict__ W_ih1, const float* __restrict__ W_hh1,
    const float* __restrict__ b_ih1, const float* __restrict__ b_hh1,
    const float* __restrict__ W_fc,  const float* __restrict__ b_fc,
    float* __restrict__ out)
{
    __shared__ _Float16 h0s[2][MB * HPAD];
    __shared__ _Float16 h1s[2][MB * HPAD];
    __shared__ float    xlds[64 * 20];       // [step-in-chunk][m], pad 20

    const int tid  = (int)threadIdx.x;
    const int lane = tid & 63;
    const int w8   = tid >> 6;          // wave 0..7
    const bool gB  = (w8 >= 4);         // group B = layer1
    const int w    = w8 & 3;            // wave within group
    const int c    = lane & 15;
    const int quad = lane >> 4;
    const int j    = (w << 4) | c;      // hidden unit owned by this lane
    const int b0   = (int)blockIdx.x * MB;

    const float L2E = 1.44269504088896340736f;

    // ---- per-group register weight fragments ----
    float biasc[4], wih0c[4];
    f16x8 bf[4][4];   // A uses [g][0..1] (W_hh0); B uses [g][0..3] ([W_ih1|W_hh1])

    if (!gB) {
#pragma unroll
        for (int g = 0; g < 4; ++g) {
            const int n = j + 64 * g;
            const float sg = (g == 2) ? (2.0f * L2E) : (-L2E);
            biasc[g] = sg * (b_ih0[n] + b_hh0[n]);
            wih0c[g] = sg * W_ih0[n];                 // D == 1
#pragma unroll
            for (int kb = 0; kb < 2; ++kb) {
                const float* p = W_hh0 + n * 64 + kb * 32 + quad * 8;
#pragma unroll
                for (int q = 0; q < 8; ++q) bf[g][kb][q] = (_Float16)(p[q] * sg);
            }
        }
    } else {
#pragma unroll
        for (int g = 0; g < 4; ++g) {
            const int n = j + 64 * g;
            const float sg = (g == 2) ? (2.0f * L2E) : (-L2E);
            biasc[g] = sg * (b_ih1[n] + b_hh1[n]);
#pragma unroll
            for (int kb = 0; kb < 4; ++kb) {
                const int kk = kb * 32 + quad * 8;
                const float* p = (kk < 64) ? (W_ih1 + n * 64 + kk)
                                           : (W_hh1 + n * 64 + (kk - 64));
#pragma unroll
                for (int q = 0; q < 8; ++q) bf[g][kb][q] = (_Float16)(p[q] * sg);
            }
        }
    }

    // zero-init h buffers (h(-1) = 0 in both parities)
    for (int i = tid; i < MB * HPAD; i += 512) {
        h0s[0][i] = (_Float16)0.f; h0s[1][i] = (_Float16)0.f;
        h1s[0][i] = (_Float16)0.f; h1s[1][i] = (_Float16)0.f;
    }

    float cst[4] = {0.f, 0.f, 0.f, 0.f};   // c0 for group A waves, c1 for group B

    for (int t = 0; t <= TSTEPS; ++t) {
        if (t < TSTEPS && (t & 63) == 0) {
            __syncthreads();                 // prior chunk's xlds reads done
            const int m  = tid >> 5;         // 0..15
            const int ii = tid & 31;         // 0..31 (coalesced over x)
            xlds[ii * 20 + m]        = x[(b0 + m) * TSTEPS + t + ii];
            xlds[(ii + 32) * 20 + m] = x[(b0 + m) * TSTEPS + t + ii + 32];
            __syncthreads();
        }

        if (!gB) {
            // ===== group A: layer0, compute h0(t) from h0(t-1), x(t) =====
            if (t < TSTEPS) {
                const int pr = (t + 1) & 1, pw = t & 1;
                const f32x4 xv = *(const f32x4*)&xlds[(t & 63) * 20 + quad * 4];
                f32x4 acc[4];
#pragma unroll
                for (int g = 0; g < 4; ++g)
#pragma unroll
                    for (int r = 0; r < 4; ++r) acc[g][r] = biasc[g] + xv[r] * wih0c[g];

                const f16x8 a0 = *(const f16x8*)&h0s[pr][c * HPAD + quad * 8];
                const f16x8 a1 = *(const f16x8*)&h0s[pr][c * HPAD + 32 + quad * 8];
#pragma unroll
                for (int g = 0; g < 4; ++g) {
                    acc[g] = __builtin_amdgcn_mfma_f32_16x16x32_f16(a0, bf[g][0], acc[g], 0, 0, 0);
                    acc[g] = __builtin_amdgcn_mfma_f32_16x16x32_f16(a1, bf[g][1], acc[g], 0, 0, 0);
                }
#pragma unroll
                for (int r = 0; r < 4; ++r) {
                    const float i_ = sig_from_scaled(acc[0][r]);
                    const float f_ = sig_from_scaled(acc[1][r]);
                    const float g_ = tanh_from_scaled(acc[2][r]);
                    const float o_ = sig_from_scaled(acc[3][r]);
                    const float cc = f_ * cst[r] + i_ * g_;
                    cst[r] = cc;
                    const float th = tanh_from_scaled(cc * (2.f * L2E));
                    h0s[pw][(quad * 4 + r) * HPAD + j] = (_Float16)(o_ * th);
                }
            }
        } else {
            // ===== group B: layer1, compute h1(s), s = t-1, from h0(s), h1(s-1) =====
            if (t > 0) {
                const int s = t - 1;
                const int prh0 = s & 1;          // h0(s) written by A at iter s
                const int prh1 = (s + 1) & 1;    // h1(s-1)
                const int pwh1 = s & 1;
                f32x4 acc[4];
#pragma unroll
                for (int g = 0; g < 4; ++g)
#pragma unroll
                    for (int r = 0; r < 4; ++r) acc[g][r] = biasc[g];

                const f16x8 a10 = *(const f16x8*)&h0s[prh0][c * HPAD + quad * 8];
                const f16x8 a11 = *(const f16x8*)&h0s[prh0][c * HPAD + 32 + quad * 8];
                const f16x8 a12 = *(const f16x8*)&h1s[prh1][c * HPAD + quad * 8];
                const f16x8 a13 = *(const f16x8*)&h1s[prh1][c * HPAD + 32 + quad * 8];
#pragma unroll
                for (int g = 0; g < 4; ++g) {
                    acc[g] = __builtin_amdgcn_mfma_f32_16x16x32_f16(a10, bf[g][0], acc[g], 0, 0, 0);
                    acc[g] = __builtin_amdgcn_mfma_f32_16x16x32_f16(a11, bf[g][1], acc[g], 0, 0, 0);
                    acc[g] = __builtin_amdgcn_mfma_f32_16x16x32_f16(a12, bf[g][2], acc[g], 0, 0, 0);
                    acc[g] = __builtin_amdgcn_mfma_f32_16x16x32_f16(a13, bf[g][3], acc[g], 0, 0, 0);
                }
#pragma unroll
                for (int r = 0; r < 4; ++r) {
                    const float i_ = sig_from_scaled(acc[0][r]);
                    const float f_ = sig_from_scaled(acc[1][r]);
                    const float g_ = tanh_from_scaled(acc[2][r]);
                    const float o_ = sig_from_scaled(acc[3][r]);
                    const float cc = f_ * cst[r] + i_ * g_;
                    cst[r] = cc;
                    const float th = tanh_from_scaled(cc * (2.f * L2E));
                    h1s[pwh1][(quad * 4 + r) * HPAD + j] = (_Float16)(o_ * th);
                }
            }
        }
        __syncthreads();
    }

    // ---- epilogue: final states. h0(511) in parity 1, h1(511) in parity 1.
    if (tid < 32) {
        const int which = tid >> 4, m = tid & 15;
        const _Float16* hb = which ? &h1s[1][m * HPAD] : &h0s[1][m * HPAD];
        float s = b_fc[0];
        for (int jj = 0; jj < 64; ++jj) s += (float)hb[jj] * W_fc[jj];
        out[which * 1024 + b0 + m] = s;
    }
}

extern "C" void kernel_launch(void* const* d_in, const int* in_sizes, int n_in,
                              void* d_out, int out_size, void* d_ws, size_t ws_size,
                              hipStream_t stream) {
    (void)in_sizes; (void)n_in; (void)d_ws; (void)ws_size; (void)out_size;
    lstm2_kernel<<<64, 512, 0, stream>>>(
        (const float*)d_in[0],
        (const float*)d_in[1], (const float*)d_in[2],
        (const float*)d_in[3], (const float*)d_in[4],
        (const float*)d_in[5], (const float*)d_in[6],
        (const float*)d_in[7], (const float*)d_in[8],
        (const float*)d_in[9], (const float*)d_in[10],
        (float*)d_out);
}